// Round 1
// baseline (9320.514 us; speedup 1.0000x reference)
//
#include <hip/hip_runtime.h>
#include <math.h>

#define T_TOTAL 32000
#define BATCH 4
#define TT 64

__device__ __forceinline__ float sigmoidf_(float x) {
    return 1.0f / (1.0f + expf(-x));
}

// ---------------- upsample network ----------------
// c1[b][o][f] = sum_j conv_in_w[o][j] * c[b][j][f]
__global__ void k_convin(const float* __restrict__ c,
                         const float* __restrict__ w,
                         float* __restrict__ c1) {
    int idx = blockIdx.x * blockDim.x + threadIdx.x;
    if (idx >= BATCH * 80 * 400) return;
    int f = idx % 400;
    int o = (idx / 400) % 80;
    int b = idx / (400 * 80);
    const float* cb = c + (size_t)b * 80 * 400 + f;
    const float* wr = w + o * 80;
    float acc = 0.f;
    #pragma unroll 8
    for (int j = 0; j < 80; ++j) acc += wr[j] * cb[(size_t)j * 400];
    c1[idx] = acc;
}

// repeat x10 then depthwise conv k=21 pad 10 : out length 4000 per channel
__global__ void k_up0(const float* __restrict__ c1, const float* __restrict__ w,
                      float* __restrict__ c2) {
    int idx = blockIdx.x * blockDim.x + threadIdx.x;
    if (idx >= BATCH * 80 * 4000) return;
    int u = idx % 4000;
    int ch = idx / 4000;              // combined b*80+ch
    const float* src = c1 + (size_t)ch * 400;
    float acc = 0.f;
    #pragma unroll
    for (int j = 0; j < 21; ++j) {
        int v = u + j - 10;
        if (v >= 0 && v < 4000) acc += w[j] * src[v / 10];
    }
    c2[idx] = acc;
}

// repeat x8 then depthwise conv k=17 pad 8 : out length 32000 per channel
__global__ void k_up1(const float* __restrict__ c2, const float* __restrict__ w,
                      float* __restrict__ cup) {
    int idx = blockIdx.x * blockDim.x + threadIdx.x;
    if (idx >= BATCH * 80 * 32000) return;
    int t = idx % 32000;
    int ch = idx / 32000;
    const float* src = c2 + (size_t)ch * 4000;
    float acc = 0.f;
    #pragma unroll
    for (int j = 0; j < 17; ++j) {
        int v = t + j - 8;
        if (v >= 0 && v < 32000) acc += w[j] * src[v >> 3];
    }
    cup[idx] = acc;
}

// ---------------- first 1x1 conv: h0 = first_w @ x + first_b ----------------
__global__ __launch_bounds__(256) void k_first(
    const float* __restrict__ x, const float* __restrict__ fw,
    const float* __restrict__ fb, float* __restrict__ h0) {
    __shared__ float xs[128][TT];
    int b = blockIdx.y;
    int t0 = blockIdx.x * TT;
    int tid = threadIdx.x;
    int lane = tid & 63;
    int wave = __builtin_amdgcn_readfirstlane(tid >> 6);
    float acc[16];
    #pragma unroll
    for (int i = 0; i < 16; ++i) acc[i] = 0.f;
    const float* xb = x + (size_t)b * 256 * T_TOTAL + t0;
    for (int kc = 0; kc < 2; ++kc) {
        for (int i = tid; i < 128 * TT; i += 256) {
            int k = i / TT, t = i % TT;
            xs[k][t] = xb[(size_t)(kc * 128 + k) * T_TOTAL + t];
        }
        __syncthreads();
        for (int k = 0; k < 128; ++k) {
            float xv = xs[k][lane];
            #pragma unroll
            for (int i = 0; i < 16; ++i)
                acc[i] += fw[(wave * 16 + i) * 256 + kc * 128 + k] * xv;
        }
        __syncthreads();
    }
    #pragma unroll
    for (int i = 0; i < 16; ++i) {
        int o = wave * 16 + i;
        h0[((size_t)b * 64 + o) * T_TOTAL + t0 + lane] = acc[i] + fb[o];
    }
}

// ---------------- fused WaveNet layer ----------------
// g = cw[:, :, 0] @ h(t-d) + cw[:, :, 1] @ h(t) + cnd @ c + cb
// z = tanh(g[:64]) * sigmoid(g[64:])
// skips (+)= sw @ z + sb ;  h_out = h_in + ow @ z + ob
__global__ __launch_bounds__(256) void k_layer(
    const float* __restrict__ h_in, float* __restrict__ h_out,
    float* __restrict__ skips, const float* __restrict__ cup,
    const float* __restrict__ cw, const float* __restrict__ cb,
    const float* __restrict__ cnd, const float* __restrict__ ow,
    const float* __restrict__ ob, const float* __restrict__ sw,
    const float* __restrict__ sb, int d, int first) {
    __shared__ float ht[64][TT];
    __shared__ float hd[64][TT];   // reused as z tile after phase 1
    __shared__ float cs[80][TT];
    int b = blockIdx.y;
    int t0 = blockIdx.x * TT;
    int tid = threadIdx.x;
    int lane = tid & 63;
    int wave = __builtin_amdgcn_readfirstlane(tid >> 6);

    const float* hb = h_in + (size_t)b * 64 * T_TOTAL;
    for (int i = tid; i < 64 * TT; i += 256) {
        int k = i / TT, t = i % TT;
        ht[k][t] = hb[(size_t)k * T_TOTAL + t0 + t];
        int td = t0 + t - d;
        hd[k][t] = (td >= 0) ? hb[(size_t)k * T_TOTAL + td] : 0.f;
    }
    const float* cbase = cup + (size_t)b * 80 * T_TOTAL;
    for (int i = tid; i < 80 * TT; i += 256) {
        int k = i / TT, t = i % TT;
        cs[k][t] = cbase[(size_t)k * T_TOTAL + t0 + t];
    }
    __syncthreads();

    // phase 1: each wave computes z rows [wave*16, wave*16+16), 2 at a time.
    // g rows (o, o+1, o+64, o+65) share each LDS read -> 1 ds_read : 4 FMA.
    float zreg[16];
    for (int zp = 0; zp < 8; ++zp) {
        int o = wave * 16 + zp * 2;
        float a0 = cb[o], a1 = cb[o + 1], g0 = cb[o + 64], g1 = cb[o + 65];
        const float* r0 = cw + (o) * 128;        // [64 k][2 taps] per row
        const float* r1 = cw + (o + 1) * 128;
        const float* r2 = cw + (o + 64) * 128;
        const float* r3 = cw + (o + 65) * 128;
        #pragma unroll 4
        for (int k = 0; k < 64; ++k) {
            float hdv = hd[k][lane];
            float htv = ht[k][lane];
            a0 += r0[k * 2] * hdv + r0[k * 2 + 1] * htv;
            a1 += r1[k * 2] * hdv + r1[k * 2 + 1] * htv;
            g0 += r2[k * 2] * hdv + r2[k * 2 + 1] * htv;
            g1 += r3[k * 2] * hdv + r3[k * 2 + 1] * htv;
        }
        const float* q0 = cnd + (o) * 80;
        const float* q1 = cnd + (o + 1) * 80;
        const float* q2 = cnd + (o + 64) * 80;
        const float* q3 = cnd + (o + 65) * 80;
        #pragma unroll 4
        for (int j = 0; j < 80; ++j) {
            float cv = cs[j][lane];
            a0 += q0[j] * cv;
            a1 += q1[j] * cv;
            g0 += q2[j] * cv;
            g1 += q3[j] * cv;
        }
        zreg[zp * 2]     = tanhf(a0) * sigmoidf_(g0);
        zreg[zp * 2 + 1] = tanhf(a1) * sigmoidf_(g1);
    }
    __syncthreads();           // all reads of hd done -> safe to overwrite
    float (*zs)[TT] = hd;
    for (int zp = 0; zp < 8; ++zp) {
        int o = wave * 16 + zp * 2;
        zs[o][lane] = zreg[zp * 2];
        zs[o + 1][lane] = zreg[zp * 2 + 1];
    }
    __syncthreads();

    // phase 2: skip and out rows; (skip o, skip o+1, out o, out o+1) share reads
    for (int rp = 0; rp < 8; ++rp) {
        int o = wave * 16 + rp * 2;
        float s0 = sb[o], s1 = sb[o + 1], u0 = ob[o], u1 = ob[o + 1];
        const float* w0 = sw + (o) * 64;
        const float* w1 = sw + (o + 1) * 64;
        const float* w2 = ow + (o) * 64;
        const float* w3 = ow + (o + 1) * 64;
        #pragma unroll 4
        for (int k = 0; k < 64; ++k) {
            float zv = zs[k][lane];
            s0 += w0[k] * zv;
            s1 += w1[k] * zv;
            u0 += w2[k] * zv;
            u1 += w3[k] * zv;
        }
        size_t i0 = ((size_t)b * 64 + o) * T_TOTAL + t0 + lane;
        size_t i1 = i0 + T_TOTAL;
        h_out[i0] = ht[o][lane] + u0;
        h_out[i1] = ht[o + 1][lane] + u1;
        if (first) { skips[i0] = s0; skips[i1] = s1; }
        else       { skips[i0] += s0; skips[i1] += s1; }
    }
}

// ---------------- last layers: relu -> 1x1 -> relu -> 1x1 ----------------
__global__ __launch_bounds__(256) void k_last(
    const float* __restrict__ skips, const float* __restrict__ w1,
    const float* __restrict__ b1, const float* __restrict__ w2,
    const float* __restrict__ b2, float* __restrict__ out) {
    __shared__ float ss[64][TT];
    __shared__ float o2[64][TT];
    int b = blockIdx.y;
    int t0 = blockIdx.x * TT;
    int tid = threadIdx.x;
    int lane = tid & 63;
    int wave = __builtin_amdgcn_readfirstlane(tid >> 6);
    const float* sbase = skips + (size_t)b * 64 * T_TOTAL;
    for (int i = tid; i < 64 * TT; i += 256) {
        int k = i / TT, t = i % TT;
        ss[k][t] = fmaxf(sbase[(size_t)k * T_TOTAL + t0 + t], 0.f);
    }
    __syncthreads();
    for (int g = 0; g < 4; ++g) {
        int o = wave * 16 + g * 4;
        float a0 = b1[o], a1 = b1[o + 1], a2 = b1[o + 2], a3 = b1[o + 3];
        #pragma unroll 4
        for (int k = 0; k < 64; ++k) {
            float v = ss[k][lane];
            a0 += w1[(o) * 64 + k] * v;
            a1 += w1[(o + 1) * 64 + k] * v;
            a2 += w1[(o + 2) * 64 + k] * v;
            a3 += w1[(o + 3) * 64 + k] * v;
        }
        o2[o][lane]     = fmaxf(a0, 0.f);
        o2[o + 1][lane] = fmaxf(a1, 0.f);
        o2[o + 2][lane] = fmaxf(a2, 0.f);
        o2[o + 3][lane] = fmaxf(a3, 0.f);
    }
    __syncthreads();
    for (int g = 0; g < 16; ++g) {
        int o = wave * 64 + g * 4;
        float a0 = b2[o], a1 = b2[o + 1], a2 = b2[o + 2], a3 = b2[o + 3];
        #pragma unroll 4
        for (int k = 0; k < 64; ++k) {
            float v = o2[k][lane];
            a0 += w2[(o) * 64 + k] * v;
            a1 += w2[(o + 1) * 64 + k] * v;
            a2 += w2[(o + 2) * 64 + k] * v;
            a3 += w2[(o + 3) * 64 + k] * v;
        }
        size_t base = ((size_t)b * 256 + o) * T_TOTAL + t0 + lane;
        out[base] = a0;
        out[base + (size_t)T_TOTAL] = a1;
        out[base + (size_t)2 * T_TOTAL] = a2;
        out[base + (size_t)3 * T_TOTAL] = a3;
    }
}

extern "C" void kernel_launch(void* const* d_in, const int* in_sizes, int n_in,
                              void* d_out, int out_size, void* d_ws, size_t ws_size,
                              hipStream_t stream) {
    const float* x        = (const float*)d_in[0];
    const float* c        = (const float*)d_in[1];
    const float* first_w  = (const float*)d_in[2];
    const float* first_b  = (const float*)d_in[3];
    const float* conv_w   = (const float*)d_in[4];
    const float* conv_b   = (const float*)d_in[5];
    const float* cond_w   = (const float*)d_in[6];
    const float* out_w    = (const float*)d_in[7];
    const float* out_b    = (const float*)d_in[8];
    const float* skip_w   = (const float*)d_in[9];
    const float* skip_b   = (const float*)d_in[10];
    const float* last1_w  = (const float*)d_in[11];
    const float* last1_b  = (const float*)d_in[12];
    const float* last2_w  = (const float*)d_in[13];
    const float* last2_b  = (const float*)d_in[14];
    const float* conv_in_w= (const float*)d_in[15];
    const float* up_w0    = (const float*)d_in[16];
    const float* up_w1    = (const float*)d_in[17];

    float* ws   = (float*)d_ws;
    float* c1   = ws;                                  //  128,000
    float* c2   = c1 + BATCH * 80 * 400;               // 1,280,000
    float* cup  = c2 + BATCH * 80 * 4000;              // 10,240,000
    float* hA   = cup + BATCH * 80 * 32000;            // 8,192,000
    float* hB   = hA + BATCH * 64 * 32000;             // 8,192,000
    float* skips= hB + BATCH * 64 * 32000;             // 8,192,000
    float* out  = (float*)d_out;

    k_convin<<<(BATCH * 80 * 400 + 255) / 256, 256, 0, stream>>>(c, conv_in_w, c1);
    k_up0<<<(BATCH * 80 * 4000 + 255) / 256, 256, 0, stream>>>(c1, up_w0, c2);
    k_up1<<<(BATCH * 80 * 32000 + 255) / 256, 256, 0, stream>>>(c2, up_w1, cup);

    dim3 grid(T_TOTAL / TT, BATCH);
    k_first<<<grid, 256, 0, stream>>>(x, first_w, first_b, hA);

    float* hin = hA;
    float* hout = hB;
    for (int l = 0; l < 30; ++l) {
        int d = 1 << (l % 10);
        k_layer<<<grid, 256, 0, stream>>>(
            hin, hout, skips, cup,
            conv_w + (size_t)l * 128 * 64 * 2, conv_b + (size_t)l * 128,
            cond_w + (size_t)l * 128 * 80,
            out_w + (size_t)l * 64 * 64, out_b + (size_t)l * 64,
            skip_w + (size_t)l * 64 * 64, skip_b + (size_t)l * 64,
            d, l == 0 ? 1 : 0);
        float* tmp = hin; hin = hout; hout = tmp;
    }

    k_last<<<grid, 256, 0, stream>>>(skips, last1_w, last1_b, last2_w, last2_b, out);
}

// Round 2
// 1881.142 us; speedup vs baseline: 4.9547x; 4.9547x over previous
//
#include <hip/hip_runtime.h>
#include <math.h>

#define T_TOTAL 32000
#define BATCH 4
#define TT 64

typedef __bf16 bf16x8 __attribute__((ext_vector_type(8)));
typedef float f32x4 __attribute__((ext_vector_type(4)));
typedef unsigned int uint4v __attribute__((ext_vector_type(4)));
typedef unsigned int uint2v __attribute__((ext_vector_type(2)));

__device__ __forceinline__ unsigned short f2b(float f) {
    unsigned int u = __float_as_uint(f);
    u += 0x7FFFu + ((u >> 16) & 1u);
    return (unsigned short)(u >> 16);
}
__device__ __forceinline__ unsigned int f2b2(float lo, float hi) {
    return (unsigned int)f2b(lo) | ((unsigned int)f2b(hi) << 16);
}
__device__ __forceinline__ bf16x8 ld_bf8(const unsigned short* p) {
    return __builtin_bit_cast(bf16x8, *(const uint4v*)p);
}
__device__ __forceinline__ float fast_sigmoid(float x) {
    return __builtin_amdgcn_rcpf(1.0f + __expf(-x));
}
__device__ __forceinline__ float fast_tanh(float x) {
    return 1.0f - 2.0f * __builtin_amdgcn_rcpf(1.0f + __expf(2.0f * x));
}

// ---------------- weight packing (fp32 -> bf16, fused/padded layouts) ----------
// wgp[l][o(128)][k(224)]: k 0..63 = conv_w[..][k][0] (tap t-d), 64..127 = tap t,
//                         128..207 = cond_w, 208..223 = 0
// wzp[l][r(128)][k(64)]:  r 0..63 = skip_w rows, 64..127 = out_w rows
__global__ void k_pack(const float* __restrict__ conv_w, const float* __restrict__ cond_w,
                       const float* __restrict__ skip_w, const float* __restrict__ out_w,
                       const float* __restrict__ first_w, const float* __restrict__ last1_w,
                       const float* __restrict__ last2_w,
                       unsigned short* __restrict__ wgp, unsigned short* __restrict__ wzp,
                       unsigned short* __restrict__ fwp, unsigned short* __restrict__ l1p,
                       unsigned short* __restrict__ l2p) {
    int i = blockIdx.x * blockDim.x + threadIdx.x;
    if (i < 860160) {  // wgp: 30*128*224
        int l = i / 28672, r = i % 28672;
        int o = r / 224, k = r % 224;
        float v;
        if (k < 64)       v = conv_w[(((size_t)l * 128 + o) * 64 + k) * 2 + 0];
        else if (k < 128) v = conv_w[(((size_t)l * 128 + o) * 64 + (k - 64)) * 2 + 1];
        else if (k < 208) v = cond_w[((size_t)l * 128 + o) * 80 + (k - 128)];
        else              v = 0.0f;
        wgp[i] = f2b(v);
        return;
    }
    i -= 860160;
    if (i < 245760) {  // wzp: 30*128*64
        int l = i / 8192, rr = (i % 8192) / 64, k = i % 64;
        float v = (rr < 64) ? skip_w[((size_t)l * 64 + rr) * 64 + k]
                            : out_w[((size_t)l * 64 + (rr - 64)) * 64 + k];
        wzp[i] = f2b(v);
        return;
    }
    i -= 245760;
    if (i < 16384) { fwp[i] = f2b(first_w[i]); return; }   // 64*256
    i -= 16384;
    if (i < 4096) { l1p[i] = f2b(last1_w[i]); return; }    // 64*64
    i -= 4096;
    if (i < 16384) { l2p[i] = f2b(last2_w[i]); return; }   // 256*64
}

// ---------------- upsample network ----------------
__global__ void k_convin(const float* __restrict__ c, const float* __restrict__ w,
                         float* __restrict__ c1) {
    int idx = blockIdx.x * blockDim.x + threadIdx.x;
    if (idx >= BATCH * 80 * 400) return;
    int f = idx % 400;
    int o = (idx / 400) % 80;
    int b = idx / (400 * 80);
    const float* cb = c + (size_t)b * 80 * 400 + f;
    const float* wr = w + o * 80;
    float acc = 0.f;
    #pragma unroll 8
    for (int j = 0; j < 80; ++j) acc += wr[j] * cb[(size_t)j * 400];
    c1[idx] = acc;
}

__global__ void k_up0(const float* __restrict__ c1, const float* __restrict__ w,
                      float* __restrict__ c2) {
    int idx = blockIdx.x * blockDim.x + threadIdx.x;
    if (idx >= BATCH * 80 * 4000) return;
    int u = idx % 4000;
    int ch = idx / 4000;
    const float* src = c1 + (size_t)ch * 400;
    float acc = 0.f;
    #pragma unroll
    for (int j = 0; j < 21; ++j) {
        int v = u + j - 10;
        if (v >= 0 && v < 4000) acc += w[j] * src[v / 10];
    }
    c2[idx] = acc;
}

// repeat x8 + 17-tap smooth, output bf16 t-major [b][t][96] (ch 80..95 zeroed pad)
__global__ void k_up1b(const float* __restrict__ c2, const float* __restrict__ w,
                       unsigned short* __restrict__ cupb) {
    int idx = blockIdx.x * blockDim.x + threadIdx.x;
    if (idx >= BATCH * T_TOTAL * 96) return;
    int ch = idx % 96;
    int t = (idx / 96) % T_TOTAL;
    int b = idx / (96 * T_TOTAL);
    if (ch >= 80) { cupb[idx] = 0; return; }
    const float* src = c2 + ((size_t)b * 80 + ch) * 4000;
    float acc = 0.f;
    #pragma unroll
    for (int j = 0; j < 17; ++j) {
        int v = t + j - 8;
        if (v >= 0 && v < T_TOTAL) acc += w[j] * src[v >> 3];
    }
    cupb[idx] = f2b(acc);
}

// ---------------- first 1x1 conv (MFMA): h0[b][t][64] = first_w @ x + b -------
__global__ __launch_bounds__(256, 4) void k_first(
    const float* __restrict__ x, const unsigned short* __restrict__ fwp,
    const float* __restrict__ fb, float* __restrict__ h0) {
    __shared__ unsigned short Xf[64 * 264];  // [t][k], row stride 264 bf16
    const int b = blockIdx.y, t0 = blockIdx.x * TT, tid = threadIdx.x;
    const int lane = tid & 63;
    const int wv = __builtin_amdgcn_readfirstlane(tid >> 6);
    const int l15 = lane & 15, q = lane >> 4;

    // stage + transpose: x is [b][256 ch][T] fp32 -> Xf[t][ch] bf16
    for (int i = tid; i < 2048; i += 256) {
        int tb = i >> 8, ch = i & 255;
        const float* xr = x + ((size_t)b * 256 + ch) * T_TOTAL + t0 + tb * 8;
        float4 u0 = *(const float4*)xr;
        float4 u1 = *(const float4*)(xr + 4);
        int base = (tb * 8) * 264 + ch;
        Xf[base + 0 * 264] = f2b(u0.x);
        Xf[base + 1 * 264] = f2b(u0.y);
        Xf[base + 2 * 264] = f2b(u0.z);
        Xf[base + 3 * 264] = f2b(u0.w);
        Xf[base + 4 * 264] = f2b(u1.x);
        Xf[base + 5 * 264] = f2b(u1.y);
        Xf[base + 6 * 264] = f2b(u1.z);
        Xf[base + 7 * 264] = f2b(u1.w);
    }
    __syncthreads();

    f32x4 acc[4] = {};
    const unsigned short* wr = fwp + (size_t)(16 * wv + l15) * 256;
    #pragma unroll
    for (int ks = 0; ks < 8; ++ks) {
        bf16x8 aA = ld_bf8(wr + ks * 32 + q * 8);
        #pragma unroll
        for (int tt = 0; tt < 4; ++tt) {
            bf16x8 bb = ld_bf8(&Xf[(tt * 16 + l15) * 264 + ks * 32 + q * 8]);
            acc[tt] = __builtin_amdgcn_mfma_f32_16x16x32_bf16(aA, bb, acc[tt], 0, 0, 0);
        }
    }
    const float4 fbv = *(const float4*)&fb[16 * wv + 4 * q];
    float* hob = h0 + (size_t)b * T_TOTAL * 64;
    #pragma unroll
    for (int tt = 0; tt < 4; ++tt) {
        size_t base = (size_t)(t0 + tt * 16 + l15) * 64 + 16 * wv + 4 * q;
        float4 ho;
        ho.x = acc[tt][0] + fbv.x;
        ho.y = acc[tt][1] + fbv.y;
        ho.z = acc[tt][2] + fbv.z;
        ho.w = acc[tt][3] + fbv.w;
        *(float4*)(hob + base) = ho;
    }
}

// ---------------- fused WaveNet layer (MFMA) ----------------
__global__ __launch_bounds__(256, 4) void k_layer(
    const float* __restrict__ h_in, float* __restrict__ h_out,
    float* __restrict__ skips, const unsigned short* __restrict__ cupb,
    const unsigned short* __restrict__ wgp, const unsigned short* __restrict__ wzp,
    const float* __restrict__ cb_l, const float* __restrict__ ob_l,
    const float* __restrict__ sb_l, int d, int first) {
    __shared__ unsigned short Xl[64 * 224];  // [t][k], k: 0..63 h(t-d), 64..127 h(t), 128..223 cond(+pad)
    __shared__ unsigned short zs[64 * 72];   // [t][o] z tile, row stride 72
    const int b = blockIdx.y, t0 = blockIdx.x * TT, tid = threadIdx.x;
    const int lane = tid & 63;
    const int wv = __builtin_amdgcn_readfirstlane(tid >> 6);
    const int l15 = lane & 15, q = lane >> 4;

    const float* hb = h_in + (size_t)b * T_TOTAL * 64;
    // stage taps (fp32 -> bf16)
    for (int i = tid; i < 512; i += 256) {
        int t = i >> 3, cb8 = (i & 7) << 3;
        const float4* p1 = (const float4*)(hb + (size_t)(t0 + t) * 64 + cb8);
        float4 u0 = p1[0], u1 = p1[1];
        uint4v v1;
        v1.x = f2b2(u0.x, u0.y); v1.y = f2b2(u0.z, u0.w);
        v1.z = f2b2(u1.x, u1.y); v1.w = f2b2(u1.z, u1.w);
        *(uint4v*)&Xl[t * 224 + 64 + cb8] = v1;
        int td = t0 + t - d;
        uint4v v0 = {0u, 0u, 0u, 0u};
        if (td >= 0) {
            const float4* p0 = (const float4*)(hb + (size_t)td * 64 + cb8);
            float4 w0 = p0[0], w1 = p0[1];
            v0.x = f2b2(w0.x, w0.y); v0.y = f2b2(w0.z, w0.w);
            v0.z = f2b2(w1.x, w1.y); v0.w = f2b2(w1.z, w1.w);
        }
        *(uint4v*)&Xl[t * 224 + cb8] = v0;
    }
    // stage conditioning (already bf16, includes zero pad ch 80..95)
    const unsigned short* cbb = cupb + (size_t)b * T_TOTAL * 96;
    for (int i = tid; i < 768; i += 256) {
        int t = i / 12, j = (i % 12) << 3;
        *(uint4v*)&Xl[t * 224 + 128 + j] = *(const uint4v*)&cbb[(size_t)(t0 + t) * 96 + j];
    }
    __syncthreads();

    // gate GEMM: wave wv owns rows {16wv..+15} (a) and {64+16wv..+15} (g), all 4 t-tiles
    f32x4 accA[4] = {}, accG[4] = {};
    const unsigned short* wrow_a = wgp + (size_t)(16 * wv + l15) * 224;
    const unsigned short* wrow_g = wgp + (size_t)(64 + 16 * wv + l15) * 224;
    #pragma unroll
    for (int ks = 0; ks < 7; ++ks) {
        bf16x8 aA = ld_bf8(wrow_a + ks * 32 + q * 8);
        bf16x8 aG = ld_bf8(wrow_g + ks * 32 + q * 8);
        #pragma unroll
        for (int tt = 0; tt < 4; ++tt) {
            bf16x8 bb = ld_bf8(&Xl[(tt * 16 + l15) * 224 + ks * 32 + q * 8]);
            accA[tt] = __builtin_amdgcn_mfma_f32_16x16x32_bf16(aA, bb, accA[tt], 0, 0, 0);
            accG[tt] = __builtin_amdgcn_mfma_f32_16x16x32_bf16(aG, bb, accG[tt], 0, 0, 0);
        }
    }
    // activation -> z tile in LDS
    const float4 cbA = *(const float4*)&cb_l[16 * wv + 4 * q];
    const float4 cbG = *(const float4*)&cb_l[64 + 16 * wv + 4 * q];
    #pragma unroll
    for (int tt = 0; tt < 4; ++tt) {
        int t = tt * 16 + l15;
        float z0 = fast_tanh(accA[tt][0] + cbA.x) * fast_sigmoid(accG[tt][0] + cbG.x);
        float z1 = fast_tanh(accA[tt][1] + cbA.y) * fast_sigmoid(accG[tt][1] + cbG.y);
        float z2 = fast_tanh(accA[tt][2] + cbA.z) * fast_sigmoid(accG[tt][2] + cbG.z);
        float z3 = fast_tanh(accA[tt][3] + cbA.w) * fast_sigmoid(accG[tt][3] + cbG.w);
        uint2v zv;
        zv.x = f2b2(z0, z1);
        zv.y = f2b2(z2, z3);
        *(uint2v*)&zs[t * 72 + 16 * wv + 4 * q] = zv;
    }
    __syncthreads();

    // z GEMM: skip rows 16wv.., out rows 64+16wv..
    f32x4 accS[4] = {}, accO[4] = {};
    const unsigned short* zrow_s = wzp + (size_t)(16 * wv + l15) * 64;
    const unsigned short* zrow_o = wzp + (size_t)(64 + 16 * wv + l15) * 64;
    #pragma unroll
    for (int ks = 0; ks < 2; ++ks) {
        bf16x8 aS = ld_bf8(zrow_s + ks * 32 + q * 8);
        bf16x8 aO = ld_bf8(zrow_o + ks * 32 + q * 8);
        #pragma unroll
        for (int tt = 0; tt < 4; ++tt) {
            bf16x8 bb = ld_bf8(&zs[(tt * 16 + l15) * 72 + ks * 32 + q * 8]);
            accS[tt] = __builtin_amdgcn_mfma_f32_16x16x32_bf16(aS, bb, accS[tt], 0, 0, 0);
            accO[tt] = __builtin_amdgcn_mfma_f32_16x16x32_bf16(aO, bb, accO[tt], 0, 0, 0);
        }
    }
    const float4 sbv = *(const float4*)&sb_l[16 * wv + 4 * q];
    const float4 obv = *(const float4*)&ob_l[16 * wv + 4 * q];
    float* hob = h_out + (size_t)b * T_TOTAL * 64;
    float* skb = skips + (size_t)b * T_TOTAL * 64;
    #pragma unroll
    for (int tt = 0; tt < 4; ++tt) {
        size_t base = (size_t)(t0 + tt * 16 + l15) * 64 + 16 * wv + 4 * q;
        float4 hi = *(const float4*)(hb + base);
        float4 ho;
        ho.x = hi.x + accO[tt][0] + obv.x;
        ho.y = hi.y + accO[tt][1] + obv.y;
        ho.z = hi.z + accO[tt][2] + obv.z;
        ho.w = hi.w + accO[tt][3] + obv.w;
        *(float4*)(hob + base) = ho;
        float4 sv;
        if (first) {
            sv.x = accS[tt][0] + sbv.x;
            sv.y = accS[tt][1] + sbv.y;
            sv.z = accS[tt][2] + sbv.z;
            sv.w = accS[tt][3] + sbv.w;
        } else {
            float4 sp = *(const float4*)(skb + base);
            sv.x = sp.x + accS[tt][0] + sbv.x;
            sv.y = sp.y + accS[tt][1] + sbv.y;
            sv.z = sp.z + accS[tt][2] + sbv.z;
            sv.w = sp.w + accS[tt][3] + sbv.w;
        }
        *(float4*)(skb + base) = sv;
    }
}

// ---------------- last layers (MFMA): relu -> 1x1 -> relu -> 1x1 -------------
__global__ __launch_bounds__(256) void k_last(
    const float* __restrict__ skips, const unsigned short* __restrict__ l1p,
    const float* __restrict__ b1, const unsigned short* __restrict__ l2p,
    const float* __restrict__ b2, float* __restrict__ out) {
    __shared__ unsigned short sp[64 * 72];
    __shared__ unsigned short o2s[64 * 72];
    const int b = blockIdx.y, t0 = blockIdx.x * TT, tid = threadIdx.x;
    const int lane = tid & 63;
    const int wv = __builtin_amdgcn_readfirstlane(tid >> 6);
    const int l15 = lane & 15, q = lane >> 4;

    const float* skb = skips + (size_t)b * T_TOTAL * 64;
    for (int i = tid; i < 512; i += 256) {
        int t = i >> 3, cb8 = (i & 7) << 3;
        const float4* p = (const float4*)(skb + (size_t)(t0 + t) * 64 + cb8);
        float4 u0 = p[0], u1 = p[1];
        uint4v v;
        v.x = f2b2(fmaxf(u0.x, 0.f), fmaxf(u0.y, 0.f));
        v.y = f2b2(fmaxf(u0.z, 0.f), fmaxf(u0.w, 0.f));
        v.z = f2b2(fmaxf(u1.x, 0.f), fmaxf(u1.y, 0.f));
        v.w = f2b2(fmaxf(u1.z, 0.f), fmaxf(u1.w, 0.f));
        *(uint4v*)&sp[t * 72 + cb8] = v;
    }
    __syncthreads();

    f32x4 a1[4] = {};
    const unsigned short* w1r = l1p + (size_t)(16 * wv + l15) * 64;
    #pragma unroll
    for (int ks = 0; ks < 2; ++ks) {
        bf16x8 aA = ld_bf8(w1r + ks * 32 + q * 8);
        #pragma unroll
        for (int tt = 0; tt < 4; ++tt) {
            bf16x8 bb = ld_bf8(&sp[(tt * 16 + l15) * 72 + ks * 32 + q * 8]);
            a1[tt] = __builtin_amdgcn_mfma_f32_16x16x32_bf16(aA, bb, a1[tt], 0, 0, 0);
        }
    }
    const float4 b1v = *(const float4*)&b1[16 * wv + 4 * q];
    #pragma unroll
    for (int tt = 0; tt < 4; ++tt) {
        int t = tt * 16 + l15;
        float z0 = fmaxf(a1[tt][0] + b1v.x, 0.f);
        float z1 = fmaxf(a1[tt][1] + b1v.y, 0.f);
        float z2 = fmaxf(a1[tt][2] + b1v.z, 0.f);
        float z3 = fmaxf(a1[tt][3] + b1v.w, 0.f);
        uint2v zv;
        zv.x = f2b2(z0, z1);
        zv.y = f2b2(z2, z3);
        *(uint2v*)&o2s[t * 72 + 16 * wv + 4 * q] = zv;
    }
    __syncthreads();

    f32x4 a2[4][4] = {};  // [j][tt]; wave wv covers output rows 64*wv .. 64*wv+63
    #pragma unroll
    for (int ks = 0; ks < 2; ++ks) {
        bf16x8 aw[4];
        #pragma unroll
        for (int j = 0; j < 4; ++j)
            aw[j] = ld_bf8(l2p + (size_t)(64 * wv + 16 * j + l15) * 64 + ks * 32 + q * 8);
        #pragma unroll
        for (int tt = 0; tt < 4; ++tt) {
            bf16x8 bb = ld_bf8(&o2s[(tt * 16 + l15) * 72 + ks * 32 + q * 8]);
            #pragma unroll
            for (int j = 0; j < 4; ++j)
                a2[j][tt] = __builtin_amdgcn_mfma_f32_16x16x32_bf16(aw[j], bb, a2[j][tt], 0, 0, 0);
        }
    }
    float* ob = out + (size_t)b * 256 * T_TOTAL;
    #pragma unroll
    for (int j = 0; j < 4; ++j) {
        int o0 = 64 * wv + 16 * j + 4 * q;
        float4 b2v = *(const float4*)&b2[o0];
        #pragma unroll
        for (int tt = 0; tt < 4; ++tt) {
            int t = t0 + tt * 16 + l15;
            ob[(size_t)(o0 + 0) * T_TOTAL + t] = a2[j][tt][0] + b2v.x;
            ob[(size_t)(o0 + 1) * T_TOTAL + t] = a2[j][tt][1] + b2v.y;
            ob[(size_t)(o0 + 2) * T_TOTAL + t] = a2[j][tt][2] + b2v.z;
            ob[(size_t)(o0 + 3) * T_TOTAL + t] = a2[j][tt][3] + b2v.w;
        }
    }
}

extern "C" void kernel_launch(void* const* d_in, const int* in_sizes, int n_in,
                              void* d_out, int out_size, void* d_ws, size_t ws_size,
                              hipStream_t stream) {
    const float* x         = (const float*)d_in[0];
    const float* c         = (const float*)d_in[1];
    const float* first_w   = (const float*)d_in[2];
    const float* first_b   = (const float*)d_in[3];
    const float* conv_w    = (const float*)d_in[4];
    const float* conv_b    = (const float*)d_in[5];
    const float* cond_w    = (const float*)d_in[6];
    const float* out_w     = (const float*)d_in[7];
    const float* out_b     = (const float*)d_in[8];
    const float* skip_w    = (const float*)d_in[9];
    const float* skip_b    = (const float*)d_in[10];
    const float* last1_w   = (const float*)d_in[11];
    const float* last1_b   = (const float*)d_in[12];
    const float* last2_w   = (const float*)d_in[13];
    const float* last2_b   = (const float*)d_in[14];
    const float* conv_in_w = (const float*)d_in[15];
    const float* up_w0     = (const float*)d_in[16];
    const float* up_w1     = (const float*)d_in[17];

    unsigned char* base = (unsigned char*)d_ws;
    float* c1            = (float*)(base + 0);            //   512,000 B
    float* c2            = (float*)(base + 512000);       // 5,120,000 B
    unsigned short* cupb = (unsigned short*)(base + 5632000);    // 24,576,000 B
    float* hA            = (float*)(base + 30208000);     // 32,768,000 B
    float* hB            = (float*)(base + 62976000);     // 32,768,000 B
    float* skips         = (float*)(base + 95744000);     // 32,768,000 B
    unsigned short* wgp  = (unsigned short*)(base + 128512000);  // 1,720,320 B
    unsigned short* wzp  = (unsigned short*)(base + 130232320);  //   491,520 B
    unsigned short* fwp  = (unsigned short*)(base + 130723840);  //    32,768 B
    unsigned short* l1p  = (unsigned short*)(base + 130756608);  //     8,192 B
    unsigned short* l2p  = (unsigned short*)(base + 130764800);  //    32,768 B

    k_pack<<<(1142784 + 255) / 256, 256, 0, stream>>>(
        conv_w, cond_w, skip_w, out_w, first_w, last1_w, last2_w,
        wgp, wzp, fwp, l1p, l2p);
    k_convin<<<(BATCH * 80 * 400 + 255) / 256, 256, 0, stream>>>(c, conv_in_w, c1);
    k_up0<<<(BATCH * 80 * 4000 + 255) / 256, 256, 0, stream>>>(c1, up_w0, c2);
    k_up1b<<<(BATCH * T_TOTAL * 96 + 255) / 256, 256, 0, stream>>>(c2, up_w1, cupb);

    dim3 grid(T_TOTAL / TT, BATCH);
    k_first<<<grid, 256, 0, stream>>>(x, fwp, first_b, hA);

    float* hin = hA;
    float* hout = hB;
    for (int l = 0; l < 30; ++l) {
        int d = 1 << (l % 10);
        k_layer<<<grid, 256, 0, stream>>>(
            hin, hout, skips, cupb,
            wgp + (size_t)l * 128 * 224, wzp + (size_t)l * 128 * 64,
            conv_b + (size_t)l * 128, out_b + (size_t)l * 64, skip_b + (size_t)l * 64,
            d, l == 0 ? 1 : 0);
        float* tmp = hin; hin = hout; hout = tmp;
    }

    k_last<<<grid, 256, 0, stream>>>(skips, l1p, last1_b, l2p, last2_b, (float*)d_out);
}